// Round 6
// baseline (334.677 us; speedup 1.0000x reference)
//
#include <hip/hip_runtime.h>
#include <hip/hip_bf16.h>

// Problem constants
#define Bb   16
#define Cc   384
#define Nn   1024
#define NH   8
#define HD   48
#define C3   1152
#define D64  64          // padded head dim for MFMA
#define KTS  72          // LDS row stride (ushorts) for K/V/GEMM tiles
#define PSTR 72          // LDS row stride for P tile [qrow][key]

typedef short  bf16x8  __attribute__((ext_vector_type(8)));
typedef float  f32x4   __attribute__((ext_vector_type(4)));
typedef unsigned short ushort8 __attribute__((ext_vector_type(8)));

__device__ inline unsigned short f2bf(float f) {
  unsigned int u = __float_as_uint(f);
  unsigned int r = (u + 0x7FFFu + ((u >> 16) & 1u)) >> 16;
  return (unsigned short)r;
}
__device__ inline float bf2f(unsigned short s) {
  return __uint_as_float(((unsigned int)s) << 16);
}
// pack two floats to bf16 pair (half-up rounding; softmax-ratio invariant)
__device__ inline unsigned int packbf(float a, float b) {
  unsigned int ua = (__float_as_uint(a) + 0x8000u) >> 16;
  unsigned int ub = (__float_as_uint(b) + 0x8000u) & 0xFFFF0000u;
  return ua | ub;
}

// ---------------------------------------------------------------------------
// Kernel A: prep — split both weight matrices to bf16 hi/lo AND fill VhT
// pad rows (48 = ones for softmax denominator, 49..63 = zeros).
// ---------------------------------------------------------------------------
__global__ __launch_bounds__(256) void prep_kernel(
    const float* __restrict__ qkv_w, const float* __restrict__ pw,
    unsigned short* __restrict__ wqh, unsigned short* __restrict__ wql,
    unsigned short* __restrict__ pwh, unsigned short* __restrict__ pwl,
    unsigned short* __restrict__ vt) {
  const int bid = blockIdx.x;
  if (bid < 1728) {
    int i = bid * 256 + threadIdx.x;
    float v = qkv_w[i];
    unsigned short hi = f2bf(v);
    wqh[i] = hi; wql[i] = f2bf(v - bf2f(hi));
  } else if (bid < 2304) {
    int i = (bid - 1728) * 256 + threadIdx.x;
    float v = pw[i];
    unsigned short hi = f2bf(v);
    pwh[i] = hi; pwl[i] = f2bf(v - bf2f(hi));
  } else {
    int idx8 = (bid - 2304) * 256 + threadIdx.x;   // 262144 ushort8 chunks
    int bh = idx8 >> 11;
    int rem = idx8 & 2047;
    int row = 48 + (rem >> 7);
    int col = (rem & 127) * 8;
    unsigned short fill = (row == 48) ? (unsigned short)0x3F80 : (unsigned short)0;
    ushort8 v;
#pragma unroll
    for (int j = 0; j < 8; j++) v[j] = fill;
    *(ushort8*)(vt + (size_t)bh * D64 * Nn + (size_t)row * Nn + col) = v;
  }
}

// ---------------------------------------------------------------------------
// Kernel B: x [B][C][N] fp32 -> xT [B][N][C] bf16.
// ---------------------------------------------------------------------------
__global__ __launch_bounds__(256) void xsplit_kernel(
    const float* __restrict__ x, unsigned short* __restrict__ xh) {
  __shared__ float tile[64][65];
  const int b  = blockIdx.z;
  const int c0 = blockIdx.y * 64;
  const int n0 = blockIdx.x * 64;
  const int t  = threadIdx.x;
  const int rl = t >> 2, sc = (t & 3) * 16;
  {
    const float* src = x + ((size_t)b * Cc + c0 + rl) * Nn + n0 + sc;
#pragma unroll
    for (int i = 0; i < 4; i++) {
      float4 v = *(const float4*)(src + i * 4);
      tile[rl][sc + i * 4 + 0] = v.x; tile[rl][sc + i * 4 + 1] = v.y;
      tile[rl][sc + i * 4 + 2] = v.z; tile[rl][sc + i * 4 + 3] = v.w;
    }
  }
  __syncthreads();
  {
    ushort8 h0, h1;
#pragma unroll
    for (int i = 0; i < 8; i++) h0[i] = f2bf(tile[sc + i][rl]);
#pragma unroll
    for (int i = 0; i < 8; i++) h1[i] = f2bf(tile[sc + 8 + i][rl]);
    size_t dst = ((size_t)b * Nn + n0 + rl) * Cc + c0 + sc;
    *(ushort8*)(xh + dst) = h0; *(ushort8*)(xh + dst + 8) = h1;
  }
}

// ---------------------------------------------------------------------------
// Kernel C: QKV GEMM, bf16 MFMA, 2-term split, register-prefetch pipeline.
// ---------------------------------------------------------------------------
__global__ __launch_bounds__(256) void qkv_mfma(
    const unsigned short* __restrict__ wh, const unsigned short* __restrict__ wl,
    const unsigned short* __restrict__ xh,
    const float* __restrict__ bias,
    unsigned short* __restrict__ qh, unsigned short* __restrict__ kh,
    unsigned short* __restrict__ vt) {
  __shared__ unsigned short Ash[128 * KTS], Asl[128 * KTS];
  __shared__ unsigned short Bsh[128 * KTS];
  const int b  = blockIdx.z;
  const int j0 = blockIdx.y * 128;
  const int n0 = blockIdx.x * 128;
  const int tid = threadIdx.x;
  const int wave = tid >> 6, lane = tid & 63;
  const int quad = lane >> 4, l16 = lane & 15;
  const int wm = (wave >> 1) * 64, wn = (wave & 1) * 64;

  const int srow = tid >> 3, sc8 = (tid & 7) * 8;   // staging row/col
  const size_t gaBase = (size_t)(j0 + srow) * Cc + sc8;
  const size_t gbBase = ((size_t)b * Nn + n0 + srow) * Cc + sc8;

  f32x4 acc[4][4];
#pragma unroll
  for (int mi = 0; mi < 4; mi++)
#pragma unroll
    for (int ni = 0; ni < 4; ni++) acc[mi][ni] = (f32x4){0.f, 0.f, 0.f, 0.f};

  uint4 rAh[2], rAl[2], rB[2];
#pragma unroll
  for (int i = 0; i < 2; i++) {       // rows srow, srow+32  (4 tiles of 32 rows? no: 128 rows / (256/8)=32 rows per pass -> 4 passes... )
    // 256 threads x 8-ushort chunks: 2048 chunks per 128x64 tile / (256) = 8 chunks per thread total across row-groups
    ;
  }
  // Each thread stages 4 row-groups (rows srow + i*32), one ushort8 per tile each.
  uint4 pAh[4], pAl[4], pB[4];
#pragma unroll
  for (int i = 0; i < 4; i++) {
    pAh[i] = *(const uint4*)(wh + gaBase + (size_t)i * 32 * Cc);
    pAl[i] = *(const uint4*)(wl + gaBase + (size_t)i * 32 * Cc);
    pB[i]  = *(const uint4*)(xh + gbBase + (size_t)i * 32 * Cc);
  }

  for (int c0 = 0; c0 < Cc; c0 += 64) {
    __syncthreads();
#pragma unroll
    for (int i = 0; i < 4; i++) {
      *(uint4*)&Ash[(srow + i * 32) * KTS + sc8] = pAh[i];
      *(uint4*)&Asl[(srow + i * 32) * KTS + sc8] = pAl[i];
      *(uint4*)&Bsh[(srow + i * 32) * KTS + sc8] = pB[i];
    }
    __syncthreads();

    if (c0 + 64 < Cc) {   // prefetch next K-chunk while computing this one
#pragma unroll
      for (int i = 0; i < 4; i++) {
        pAh[i] = *(const uint4*)(wh + gaBase + (size_t)i * 32 * Cc + c0 + 64);
        pAl[i] = *(const uint4*)(wl + gaBase + (size_t)i * 32 * Cc + c0 + 64);
        pB[i]  = *(const uint4*)(xh + gbBase + (size_t)i * 32 * Cc + c0 + 64);
      }
    }

#pragma unroll
    for (int ks = 0; ks < 64; ks += 32) {
      bf16x8 ah[4], al[4], bh[4];
#pragma unroll
      for (int mi = 0; mi < 4; mi++) {
        int base = (wm + mi * 16 + l16) * KTS + ks + quad * 8;
        ah[mi] = *(const bf16x8*)&Ash[base];
        al[mi] = *(const bf16x8*)&Asl[base];
      }
#pragma unroll
      for (int ni = 0; ni < 4; ni++) {
        int base = (wn + ni * 16 + l16) * KTS + ks + quad * 8;
        bh[ni] = *(const bf16x8*)&Bsh[base];
      }
#pragma unroll
      for (int mi = 0; mi < 4; mi++)
#pragma unroll
        for (int ni = 0; ni < 4; ni++) {
          acc[mi][ni] = __builtin_amdgcn_mfma_f32_16x16x32_bf16(ah[mi], bh[ni], acc[mi][ni], 0, 0, 0);
          acc[mi][ni] = __builtin_amdgcn_mfma_f32_16x16x32_bf16(al[mi], bh[ni], acc[mi][ni], 0, 0, 0);
        }
    }
  }

  const int part = (j0 >= 768) ? 2 : (j0 >= 384 ? 1 : 0);
  unsigned short* dstq = (part == 0) ? qh : kh;
#pragma unroll
  for (int mi = 0; mi < 4; mi++) {
#pragma unroll
    for (int r = 0; r < 4; r++) {
      int j = j0 + wm + mi * 16 + quad * 4 + r;
      int jl = j - part * Cc;
      int h = jl / HD, d = jl % HD;
      float bv = bias[j];
      if (part < 2) {
#pragma unroll
        for (int ni = 0; ni < 4; ni++) {
          int n = n0 + wn + ni * 16 + l16;
          dstq[((size_t)(b * NH + h) * Nn + n) * D64 + d] = f2bf(acc[mi][ni][r] + bv);
        }
      } else {
        unsigned short* vrow = vt + ((size_t)(b * NH + h) * D64 + d) * Nn;
#pragma unroll
        for (int ni = 0; ni < 4; ni++) {
          int n = n0 + wn + ni * 16 + l16;
          vrow[n] = f2bf(acc[mi][ni][r] + bv);
        }
      }
    }
  }
}

// ---------------------------------------------------------------------------
// Kernel D: in-place L2 norm of q,k rows + zero dim pads 48..63.
// ---------------------------------------------------------------------------
__global__ __launch_bounds__(256) void normqk_kernel(
    unsigned short* __restrict__ qh, unsigned short* __restrict__ kh) {
  const int tid = threadIdx.x;
  const int row = blockIdx.x * 16 + (tid >> 4);
  const int l16 = tid & 15;
  const int TOT = Bb * NH * Nn;
  unsigned short* buf = (row < TOT) ? qh : kh;
  int r = (row < TOT) ? row : row - TOT;
  unsigned short* rowb = buf + (size_t)r * D64;
  unsigned short* p = rowb + l16 * 3;
  float a = bf2f(p[0]), b = bf2f(p[1]), c = bf2f(p[2]);
  float ss = a * a + b * b + c * c;
  ss += __shfl_xor(ss, 1, 16);
  ss += __shfl_xor(ss, 2, 16);
  ss += __shfl_xor(ss, 4, 16);
  ss += __shfl_xor(ss, 8, 16);
  float scale = 1.0f / fmaxf(sqrtf(ss), 1e-12f);
  p[0] = f2bf(a * scale); p[1] = f2bf(b * scale); p[2] = f2bf(c * scale);
  if (l16 < 8) ((unsigned int*)(rowb + HD))[l16] = 0u;
}

// ---------------------------------------------------------------------------
// Kernel E: MFMA flash attention, transposed data path + SW pipeline.
// ---------------------------------------------------------------------------
__global__ __launch_bounds__(256, 4) void attn_mfma(
    const unsigned short* __restrict__ qh, const unsigned short* __restrict__ kh,
    const unsigned short* __restrict__ vt, const float* __restrict__ temp,
    unsigned short* __restrict__ obh) {
  __shared__ unsigned short Kt[64 * KTS];
  __shared__ unsigned short Vt[64 * KTS];
  __shared__ unsigned short Pt[4 * 32 * PSTR];

  const int bid = blockIdx.x;
  const int hb = bid & 127;
  const int q0 = (bid >> 7) * 128;
  const int b = hb >> 3, h = hb & 7;
  const int tid = threadIdx.x;
  const int wave = tid >> 6, lane = tid & 63;
  const int quad = lane >> 4, l16 = lane & 15;

  const size_t headQ = ((size_t)(b * NH + h) * Nn) * D64;
  const unsigned short* Qg = qh + headQ + (size_t)(q0 + wave * 32) * D64;
  const unsigned short* Kg = kh + headQ;
  const unsigned short* Vg = vt + ((size_t)(b * NH + h) * D64) * Nn;

  bf16x8 qa0[2], qa1[2];
#pragma unroll
  for (int m = 0; m < 2; m++) {
    qa0[m] = *(const bf16x8*)(Qg + (m * 16 + l16) * D64 + quad * 8);
    qa1[m] = *(const bf16x8*)(Qg + (m * 16 + l16) * D64 + quad * 8 + 32);
  }

  const float T2 = temp[h] * 1.44269504f;
  const float M2 = fabsf(T2);

  f32x4 oacc[2][4];
#pragma unroll
  for (int m = 0; m < 2; m++)
#pragma unroll
    for (int g = 0; g < 4; g++) oacc[m][g] = (f32x4){0.f, 0.f, 0.f, 0.f};
  const f32x4 zf = (f32x4){0.f, 0.f, 0.f, 0.f};

  unsigned short* Ptw = Pt + wave * 32 * PSTR;
  const int skey = tid >> 2;
  const int spart = (tid & 3) * 16;

  const unsigned short* ksrc = Kg + (size_t)skey * D64 + spart;
  const unsigned short* vsrc = Vg + (size_t)skey * Nn + spart;
  unsigned short* kdst = Kt + skey * KTS + spart;
  unsigned short* vdst = Vt + skey * KTS + spart;

  uint4 kr0 = *(const uint4*)(ksrc);
  uint4 kr1 = *(const uint4*)(ksrc + 8);
  uint4 vr0 = *(const uint4*)(vsrc);
  uint4 vr1 = *(const uint4*)(vsrc + 8);

  for (int kt = 0; kt < Nn / 64; kt++) {
    __syncthreads();
    *(uint4*)kdst = kr0;
    *(uint4*)(kdst + 8) = kr1;
    *(uint4*)vdst = vr0;
    *(uint4*)(vdst + 8) = vr1;
    __syncthreads();

    if (kt < Nn / 64 - 1) {
      const unsigned short* kn = ksrc + (size_t)(kt + 1) * 64 * D64;
      const unsigned short* vn = vsrc + (size_t)(kt + 1) * 64;
      kr0 = *(const uint4*)kn;
      kr1 = *(const uint4*)(kn + 8);
      vr0 = *(const uint4*)vn;
      vr1 = *(const uint4*)(vn + 8);
    }

    f32x4 sT[2][4];
#pragma unroll
    for (int g = 0; g < 4; g++) {
      const unsigned short* kb = Kt + (g * 16 + l16) * KTS + quad * 8;
      bf16x8 kf0 = *(const bf16x8*)kb;
      bf16x8 kf1 = *(const bf16x8*)(kb + 32);
#pragma unroll
      for (int m = 0; m < 2; m++) {
        f32x4 s = __builtin_amdgcn_mfma_f32_16x16x32_bf16(kf0, qa0[m], zf, 0, 0, 0);
        sT[m][g] = __builtin_amdgcn_mfma_f32_16x16x32_bf16(kf1, qa1[m], s, 0, 0, 0);
      }
    }

#pragma unroll
    for (int m = 0; m < 2; m++) {
#pragma unroll
      for (int g = 0; g < 4; g++) {
        uint2 pw;
        pw.x = packbf(__builtin_amdgcn_exp2f(sT[m][g][0] * T2 - M2),
                      __builtin_amdgcn_exp2f(sT[m][g][1] * T2 - M2));
        pw.y = packbf(__builtin_amdgcn_exp2f(sT[m][g][2] * T2 - M2),
                      __builtin_amdgcn_exp2f(sT[m][g][3] * T2 - M2));
        *(uint2*)(Ptw + (m * 16 + l16) * PSTR + g * 16 + quad * 4) = pw;
      }
    }

    bf16x8 pa[2][2];
#pragma unroll
    for (int m = 0; m < 2; m++) {
      pa[m][0] = *(const bf16x8*)(Ptw + (m * 16 + l16) * PSTR + quad * 8);
      pa[m][1] = *(const bf16x8*)(Ptw + (m * 16 + l16) * PSTR + quad * 8 + 32);
    }

#pragma unroll
    for (int g = 0; g < 4; g++) {
      const unsigned short* vb0 = Vt + (g * 16 + l16) * KTS + quad * 8;
      bf16x8 vf0 = *(const bf16x8*)vb0;
      bf16x8 vf1 = *(const bf16x8*)(vb0 + 32);
#pragma unroll
      for (int m = 0; m < 2; m++) {
        oacc[m][g] = __builtin_amdgcn_mfma_f32_16x16x32_bf16(vf0, pa[m][0], oacc[m][g], 0, 0, 0);
        oacc[m][g] = __builtin_amdgcn_mfma_f32_16x16x32_bf16(vf1, pa[m][1], oacc[m][g], 0, 0, 0);
      }
    }
  }

#pragma unroll
  for (int m = 0; m < 2; m++) {
    float inv = 1.0f / __shfl(oacc[m][3][0], l16);
    size_t obase = ((size_t)b * Nn + q0 + wave * 32 + m * 16 + l16) * Cc + h * HD;
#pragma unroll
    for (int g = 0; g < 3; g++) {
      ushort4 sv;
      sv.x = f2bf(oacc[m][g][0] * inv);
      sv.y = f2bf(oacc[m][g][1] * inv);
      sv.z = f2bf(oacc[m][g][2] * inv);
      sv.w = f2bf(oacc[m][g][3] * inv);
      *(ushort4*)(obh + obase + g * 16 + quad * 4) = sv;
    }
  }
}

// ---------------------------------------------------------------------------
// Kernel F: projection GEMM, 2-term split, register-prefetch pipeline.
// ---------------------------------------------------------------------------
__global__ __launch_bounds__(256) void proj_mfma(
    const unsigned short* __restrict__ pwh, const unsigned short* __restrict__ pwl,
    const unsigned short* __restrict__ obh,
    const float* __restrict__ pb, float* __restrict__ out) {
  __shared__ unsigned short Ash[128 * KTS], Asl[128 * KTS];
  __shared__ unsigned short Bsh[128 * KTS];
  const int b  = blockIdx.z;
  const int c0m = blockIdx.y * 128;
  const int n0 = blockIdx.x * 128;
  const int tid = threadIdx.x;
  const int wave = tid >> 6, lane = tid & 63;
  const int quad = lane >> 4, l16 = lane & 15;
  const int wm = (wave >> 1) * 64, wn = (wave & 1) * 64;

  const int srow = tid >> 3, sc8 = (tid & 7) * 8;
  const size_t gaBase = (size_t)(c0m + srow) * Cc + sc8;
  const size_t gbBase = ((size_t)b * Nn + n0 + srow) * Cc + sc8;

  f32x4 acc[4][4];
#pragma unroll
  for (int mi = 0; mi < 4; mi++)
#pragma unroll
    for (int ni = 0; ni < 4; ni++) acc[mi][ni] = (f32x4){0.f, 0.f, 0.f, 0.f};

  uint4 pAh[4], pAl[4], pB[4];
#pragma unroll
  for (int i = 0; i < 4; i++) {
    pAh[i] = *(const uint4*)(pwh + gaBase + (size_t)i * 32 * Cc);
    pAl[i] = *(const uint4*)(pwl + gaBase + (size_t)i * 32 * Cc);
    pB[i]  = *(const uint4*)(obh + gbBase + (size_t)i * 32 * Cc);
  }

  for (int j0 = 0; j0 < Cc; j0 += 64) {
    __syncthreads();
#pragma unroll
    for (int i = 0; i < 4; i++) {
      *(uint4*)&Ash[(srow + i * 32) * KTS + sc8] = pAh[i];
      *(uint4*)&Asl[(srow + i * 32) * KTS + sc8] = pAl[i];
      *(uint4*)&Bsh[(srow + i * 32) * KTS + sc8] = pB[i];
    }
    __syncthreads();

    if (j0 + 64 < Cc) {
#pragma unroll
      for (int i = 0; i < 4; i++) {
        pAh[i] = *(const uint4*)(pwh + gaBase + (size_t)i * 32 * Cc + j0 + 64);
        pAl[i] = *(const uint4*)(pwl + gaBase + (size_t)i * 32 * Cc + j0 + 64);
        pB[i]  = *(const uint4*)(obh + gbBase + (size_t)i * 32 * Cc + j0 + 64);
      }
    }

#pragma unroll
    for (int ks = 0; ks < 64; ks += 32) {
      bf16x8 ah[4], al[4], bh[4];
#pragma unroll
      for (int mi = 0; mi < 4; mi++) {
        int base = (wm + mi * 16 + l16) * KTS + ks + quad * 8;
        ah[mi] = *(const bf16x8*)&Ash[base];
        al[mi] = *(const bf16x8*)&Asl[base];
      }
#pragma unroll
      for (int ni = 0; ni < 4; ni++) {
        int base = (wn + ni * 16 + l16) * KTS + ks + quad * 8;
        bh[ni] = *(const bf16x8*)&Bsh[base];
      }
#pragma unroll
      for (int mi = 0; mi < 4; mi++)
#pragma unroll
        for (int ni = 0; ni < 4; ni++) {
          acc[mi][ni] = __builtin_amdgcn_mfma_f32_16x16x32_bf16(ah[mi], bh[ni], acc[mi][ni], 0, 0, 0);
          acc[mi][ni] = __builtin_amdgcn_mfma_f32_16x16x32_bf16(al[mi], bh[ni], acc[mi][ni], 0, 0, 0);
        }
    }
  }

#pragma unroll
  for (int mi = 0; mi < 4; mi++) {
#pragma unroll
    for (int r = 0; r < 4; r++) {
      int c = c0m + wm + mi * 16 + quad * 4 + r;
      float bv = pb[c];
#pragma unroll
      for (int ni = 0; ni < 4; ni++) {
        int n = n0 + wn + ni * 16 + l16;
        out[((size_t)b * Cc + c) * Nn + n] = acc[mi][ni][r] + bv;
      }
    }
  }
}

// ---------------------------------------------------------------------------
extern "C" void kernel_launch(void* const* d_in, const int* in_sizes, int n_in,
                              void* d_out, int out_size, void* d_ws, size_t ws_size,
                              hipStream_t stream) {
  const float* x     = (const float*)d_in[0];
  const float* temp  = (const float*)d_in[1];
  const float* qkv_w = (const float*)d_in[2];
  const float* qkv_b = (const float*)d_in[3];
  const float* pw    = (const float*)d_in[4];
  const float* pb    = (const float*)d_in[5];
  float* out = (float*)d_out;

  const size_t QKN = (size_t)Bb * NH * Nn * D64;   // 8,388,608
  const size_t WQN = (size_t)C3 * Cc;              // 442,368
  const size_t PWN = (size_t)Cc * Cc;              // 147,456

  unsigned short* Qh  = (unsigned short*)d_ws;
  unsigned short* Kh  = Qh + QKN;
  unsigned short* VhT = Kh + QKN;                  // [B][NH][64][N]
  unsigned short* Wqh = VhT + QKN;
  unsigned short* Wql = Wqh + WQN;
  unsigned short* Pwh = Wql + WQN;
  unsigned short* Pwl = Pwh + PWN;
  unsigned short* Xth = Pwl + PWN;                 // aliased by Obh after qkv
  unsigned short* Obh = Xth;

  prep_kernel<<<3328, 256, 0, stream>>>(qkv_w, pw, Wqh, Wql, Pwh, Pwl, VhT);
  xsplit_kernel<<<dim3(Nn / 64, Cc / 64, Bb), 256, 0, stream>>>(x, Xth);
  qkv_mfma<<<dim3(Nn / 128, C3 / 128, Bb), 256, 0, stream>>>(Wqh, Wql, Xth, qkv_b, Qh, Kh, VhT);
  normqk_kernel<<<(2 * Bb * NH * Nn) / 16, 256, 0, stream>>>(Qh, Kh);
  attn_mfma<<<1024, 256, 0, stream>>>(Qh, Kh, VhT, temp, Obh);
  proj_mfma<<<dim3(Nn / 128, Cc / 128, Bb), 256, 0, stream>>>(Pwh, Pwl, Obh, pb, out);
}

// Round 7
// 221.433 us; speedup vs baseline: 1.5114x; 1.5114x over previous
//
#include <hip/hip_runtime.h>
#include <hip/hip_bf16.h>

// Problem constants
#define Bb   16
#define Cc   384
#define Nn   1024
#define NH   8
#define HD   48
#define C3   1152
#define D64  64          // padded head dim for MFMA
#define KTS  72          // LDS row stride (ushorts) for attn K/V tiles
#define PSTR 72          // LDS row stride for attn P tile

typedef short  bf16x8  __attribute__((ext_vector_type(8)));
typedef float  f32x4   __attribute__((ext_vector_type(4)));
typedef unsigned short ushort8 __attribute__((ext_vector_type(8)));

__device__ inline unsigned short f2bf(float f) {
  unsigned int u = __float_as_uint(f);
  unsigned int r = (u + 0x7FFFu + ((u >> 16) & 1u)) >> 16;
  return (unsigned short)r;
}
__device__ inline float bf2f(unsigned short s) {
  return __uint_as_float(((unsigned int)s) << 16);
}
__device__ inline unsigned int packbf(float a, float b) {
  unsigned int ua = (__float_as_uint(a) + 0x8000u) >> 16;
  unsigned int ub = (__float_as_uint(b) + 0x8000u) & 0xFFFF0000u;
  return ua | ub;
}

// async 16B global->LDS (no VGPR round-trip). lds dest = wave-uniform base
// + lane*16; all lanes must pass the same lds base.
__device__ inline void gload_lds16(const unsigned short* g, unsigned short* l) {
  __builtin_amdgcn_global_load_lds(
      (const __attribute__((address_space(1))) void*)g,
      (__attribute__((address_space(3))) void*)l, 16, 0, 0);
}

// ---------------------------------------------------------------------------
// Kernel A: prep — weight hi/lo splits + VhT pad rows (48=ones, 49..63=0).
// ---------------------------------------------------------------------------
__global__ __launch_bounds__(256) void prep_kernel(
    const float* __restrict__ qkv_w, const float* __restrict__ pw,
    unsigned short* __restrict__ wqh, unsigned short* __restrict__ wql,
    unsigned short* __restrict__ pwh, unsigned short* __restrict__ pwl,
    unsigned short* __restrict__ vt) {
  const int bid = blockIdx.x;
  if (bid < 1728) {
    int i = bid * 256 + threadIdx.x;
    float v = qkv_w[i];
    unsigned short hi = f2bf(v);
    wqh[i] = hi; wql[i] = f2bf(v - bf2f(hi));
  } else if (bid < 2304) {
    int i = (bid - 1728) * 256 + threadIdx.x;
    float v = pw[i];
    unsigned short hi = f2bf(v);
    pwh[i] = hi; pwl[i] = f2bf(v - bf2f(hi));
  } else {
    int idx8 = (bid - 2304) * 256 + threadIdx.x;
    int bh = idx8 >> 11;
    int rem = idx8 & 2047;
    int row = 48 + (rem >> 7);
    int col = (rem & 127) * 8;
    unsigned short fill = (row == 48) ? (unsigned short)0x3F80 : (unsigned short)0;
    ushort8 v;
#pragma unroll
    for (int j = 0; j < 8; j++) v[j] = fill;
    *(ushort8*)(vt + (size_t)bh * D64 * Nn + (size_t)row * Nn + col) = v;
  }
}

// ---------------------------------------------------------------------------
// Kernel B: x [B][C][N] fp32 -> xT [B][N][C] bf16.
// ---------------------------------------------------------------------------
__global__ __launch_bounds__(256) void xsplit_kernel(
    const float* __restrict__ x, unsigned short* __restrict__ xh) {
  __shared__ float tile[64][65];
  const int b  = blockIdx.z;
  const int c0 = blockIdx.y * 64;
  const int n0 = blockIdx.x * 64;
  const int t  = threadIdx.x;
  const int rl = t >> 2, sc = (t & 3) * 16;
  {
    const float* src = x + ((size_t)b * Cc + c0 + rl) * Nn + n0 + sc;
#pragma unroll
    for (int i = 0; i < 4; i++) {
      float4 v = *(const float4*)(src + i * 4);
      tile[rl][sc + i * 4 + 0] = v.x; tile[rl][sc + i * 4 + 1] = v.y;
      tile[rl][sc + i * 4 + 2] = v.z; tile[rl][sc + i * 4 + 3] = v.w;
    }
  }
  __syncthreads();
  {
    ushort8 h0, h1;
#pragma unroll
    for (int i = 0; i < 8; i++) h0[i] = f2bf(tile[sc + i][rl]);
#pragma unroll
    for (int i = 0; i < 8; i++) h1[i] = f2bf(tile[sc + 8 + i][rl]);
    size_t dst = ((size_t)b * Nn + n0 + rl) * Cc + c0 + sc;
    *(ushort8*)(xh + dst) = h0; *(ushort8*)(xh + dst + 8) = h1;
  }
}

// ---------------------------------------------------------------------------
// Kernel C: QKV GEMM, bf16 MFMA, 2-term split, async global_load_lds staging.
// LDS tiles 128x64, no pad; XOR swizzle chunk' = chunk ^ (row&7).
// Fragment reads invert the swizzle via ^(l16&7).
// ---------------------------------------------------------------------------
__global__ __launch_bounds__(256, 3) void qkv_mfma(
    const unsigned short* __restrict__ wh, const unsigned short* __restrict__ wl,
    const unsigned short* __restrict__ xh,
    const float* __restrict__ bias,
    unsigned short* __restrict__ qh, unsigned short* __restrict__ kh,
    unsigned short* __restrict__ vt) {
  __shared__ unsigned short Ash[128 * 64];
  __shared__ unsigned short Asl[128 * 64];
  __shared__ unsigned short Bsh[128 * 64];
  const int b  = blockIdx.z;
  const int j0 = blockIdx.y * 128;
  const int n0 = blockIdx.x * 128;
  const int tid = threadIdx.x;
  const int wave = tid >> 6, lane = tid & 63;
  const int quad = lane >> 4, l16 = lane & 15;
  const int wm = (wave >> 1) * 64, wn = (wave & 1) * 64;

  // staging: wave w covers rows w*32..w*32+31 (4 segments of 8 rows) per tile
  const int lrow = lane >> 3;    // row within segment (0..7)
  const int lch  = lane & 7;     // LDS chunk within row (16B units)

  f32x4 acc[4][4];
#pragma unroll
  for (int mi = 0; mi < 4; mi++)
#pragma unroll
    for (int ni = 0; ni < 4; ni++) acc[mi][ni] = (f32x4){0.f, 0.f, 0.f, 0.f};

  const int sw = l16 & 7;        // fragment-read swizzle

  for (int c0 = 0; c0 < Cc; c0 += 64) {
    __syncthreads();
#pragma unroll
    for (int seg = 0; seg < 4; seg++) {
      int r  = wave * 32 + seg * 8 + lrow;          // tile row 0..127
      int cg = (lch ^ (r & 7)) * 8;                 // swizzled global chunk
      int lofs = (wave * 32 + seg * 8) * 64;        // wave-uniform seg base
      size_t gA = (size_t)(j0 + r) * Cc + c0 + cg;
      size_t gB = ((size_t)b * Nn + n0 + r) * Cc + c0 + cg;
      gload_lds16(wh + gA, &Ash[lofs]);
      gload_lds16(wl + gA, &Asl[lofs]);
      gload_lds16(xh + gB, &Bsh[lofs]);
    }
    __syncthreads();   // drains vmcnt(0): staging complete

#pragma unroll
    for (int ks = 0; ks < 64; ks += 32) {
      const int ach = (((ks >> 3) + quad) ^ sw) * 8;   // de-swizzled column
      bf16x8 ah[4], al[4], bh[4];
#pragma unroll
      for (int mi = 0; mi < 4; mi++) {
        int rowA = (wm + mi * 16 + l16) * 64;
        ah[mi] = *(const bf16x8*)&Ash[rowA + ach];
        al[mi] = *(const bf16x8*)&Asl[rowA + ach];
      }
#pragma unroll
      for (int ni = 0; ni < 4; ni++) {
        int rowB = (wn + ni * 16 + l16) * 64;
        bh[ni] = *(const bf16x8*)&Bsh[rowB + ach];
      }
#pragma unroll
      for (int mi = 0; mi < 4; mi++)
#pragma unroll
        for (int ni = 0; ni < 4; ni++) {
          acc[mi][ni] = __builtin_amdgcn_mfma_f32_16x16x32_bf16(ah[mi], bh[ni], acc[mi][ni], 0, 0, 0);
          acc[mi][ni] = __builtin_amdgcn_mfma_f32_16x16x32_bf16(al[mi], bh[ni], acc[mi][ni], 0, 0, 0);
        }
    }
  }

  const int part = (j0 >= 768) ? 2 : (j0 >= 384 ? 1 : 0);
  unsigned short* dstq = (part == 0) ? qh : kh;
#pragma unroll
  for (int mi = 0; mi < 4; mi++) {
#pragma unroll
    for (int r = 0; r < 4; r++) {
      int j = j0 + wm + mi * 16 + quad * 4 + r;
      int jl = j - part * Cc;
      int h = jl / HD, d = jl % HD;
      float bv = bias[j];
      if (part < 2) {
#pragma unroll
        for (int ni = 0; ni < 4; ni++) {
          int n = n0 + wn + ni * 16 + l16;
          dstq[((size_t)(b * NH + h) * Nn + n) * D64 + d] = f2bf(acc[mi][ni][r] + bv);
        }
      } else {
        unsigned short* vrow = vt + ((size_t)(b * NH + h) * D64 + d) * Nn;
#pragma unroll
        for (int ni = 0; ni < 4; ni++) {
          int n = n0 + wn + ni * 16 + l16;
          vrow[n] = f2bf(acc[mi][ni][r] + bv);
        }
      }
    }
  }
}

// ---------------------------------------------------------------------------
// Kernel D: in-place L2 norm of q,k rows + zero dim pads 48..63.
// ---------------------------------------------------------------------------
__global__ __launch_bounds__(256) void normqk_kernel(
    unsigned short* __restrict__ qh, unsigned short* __restrict__ kh) {
  const int tid = threadIdx.x;
  const int row = blockIdx.x * 16 + (tid >> 4);
  const int l16 = tid & 15;
  const int TOT = Bb * NH * Nn;
  unsigned short* buf = (row < TOT) ? qh : kh;
  int r = (row < TOT) ? row : row - TOT;
  unsigned short* rowb = buf + (size_t)r * D64;
  unsigned short* p = rowb + l16 * 3;
  float a = bf2f(p[0]), b = bf2f(p[1]), c = bf2f(p[2]);
  float ss = a * a + b * b + c * c;
  ss += __shfl_xor(ss, 1, 16);
  ss += __shfl_xor(ss, 2, 16);
  ss += __shfl_xor(ss, 4, 16);
  ss += __shfl_xor(ss, 8, 16);
  float scale = 1.0f / fmaxf(sqrtf(ss), 1e-12f);
  p[0] = f2bf(a * scale); p[1] = f2bf(b * scale); p[2] = f2bf(c * scale);
  if (l16 < 8) ((unsigned int*)(rowb + HD))[l16] = 0u;
}

// ---------------------------------------------------------------------------
// Kernel E: MFMA flash attention (unchanged from R5's working version).
// ---------------------------------------------------------------------------
__global__ __launch_bounds__(256, 4) void attn_mfma(
    const unsigned short* __restrict__ qh, const unsigned short* __restrict__ kh,
    const unsigned short* __restrict__ vt, const float* __restrict__ temp,
    unsigned short* __restrict__ obh) {
  __shared__ unsigned short Kt[64 * KTS];
  __shared__ unsigned short Vt[64 * KTS];
  __shared__ unsigned short Pt[4 * 32 * PSTR];

  const int bid = blockIdx.x;
  const int hb = bid & 127;
  const int q0 = (bid >> 7) * 128;
  const int b = hb >> 3, h = hb & 7;
  const int tid = threadIdx.x;
  const int wave = tid >> 6, lane = tid & 63;
  const int quad = lane >> 4, l16 = lane & 15;

  const size_t headQ = ((size_t)(b * NH + h) * Nn) * D64;
  const unsigned short* Qg = qh + headQ + (size_t)(q0 + wave * 32) * D64;
  const unsigned short* Kg = kh + headQ;
  const unsigned short* Vg = vt + ((size_t)(b * NH + h) * D64) * Nn;

  bf16x8 qa0[2], qa1[2];
#pragma unroll
  for (int m = 0; m < 2; m++) {
    qa0[m] = *(const bf16x8*)(Qg + (m * 16 + l16) * D64 + quad * 8);
    qa1[m] = *(const bf16x8*)(Qg + (m * 16 + l16) * D64 + quad * 8 + 32);
  }

  const float T2 = temp[h] * 1.44269504f;
  const float M2 = fabsf(T2);

  f32x4 oacc[2][4];
#pragma unroll
  for (int m = 0; m < 2; m++)
#pragma unroll
    for (int g = 0; g < 4; g++) oacc[m][g] = (f32x4){0.f, 0.f, 0.f, 0.f};
  const f32x4 zf = (f32x4){0.f, 0.f, 0.f, 0.f};

  unsigned short* Ptw = Pt + wave * 32 * PSTR;
  const int skey = tid >> 2;
  const int spart = (tid & 3) * 16;

  const unsigned short* ksrc = Kg + (size_t)skey * D64 + spart;
  const unsigned short* vsrc = Vg + (size_t)skey * Nn + spart;
  unsigned short* kdst = Kt + skey * KTS + spart;
  unsigned short* vdst = Vt + skey * KTS + spart;

  uint4 kr0 = *(const uint4*)(ksrc);
  uint4 kr1 = *(const uint4*)(ksrc + 8);
  uint4 vr0 = *(const uint4*)(vsrc);
  uint4 vr1 = *(const uint4*)(vsrc + 8);

  for (int kt = 0; kt < Nn / 64; kt++) {
    __syncthreads();
    *(uint4*)kdst = kr0;
    *(uint4*)(kdst + 8) = kr1;
    *(uint4*)vdst = vr0;
    *(uint4*)(vdst + 8) = vr1;
    __syncthreads();

    if (kt < Nn / 64 - 1) {
      const unsigned short* kn = ksrc + (size_t)(kt + 1) * 64 * D64;
      const unsigned short* vn = vsrc + (size_t)(kt + 1) * 64;
      kr0 = *(const uint4*)kn;
      kr1 = *(const uint4*)(kn + 8);
      vr0 = *(const uint4*)vn;
      vr1 = *(const uint4*)(vn + 8);
    }

    f32x4 sT[2][4];
#pragma unroll
    for (int g = 0; g < 4; g++) {
      const unsigned short* kb = Kt + (g * 16 + l16) * KTS + quad * 8;
      bf16x8 kf0 = *(const bf16x8*)kb;
      bf16x8 kf1 = *(const bf16x8*)(kb + 32);
#pragma unroll
      for (int m = 0; m < 2; m++) {
        f32x4 s = __builtin_amdgcn_mfma_f32_16x16x32_bf16(kf0, qa0[m], zf, 0, 0, 0);
        sT[m][g] = __builtin_amdgcn_mfma_f32_16x16x32_bf16(kf1, qa1[m], s, 0, 0, 0);
      }
    }

#pragma unroll
    for (int m = 0; m < 2; m++) {
#pragma unroll
      for (int g = 0; g < 4; g++) {
        uint2 pw;
        pw.x = packbf(__builtin_amdgcn_exp2f(sT[m][g][0] * T2 - M2),
                      __builtin_amdgcn_exp2f(sT[m][g][1] * T2 - M2));
        pw.y = packbf(__builtin_amdgcn_exp2f(sT[m][g][2] * T2 - M2),
                      __builtin_amdgcn_exp2f(sT[m][g][3] * T2 - M2));
        *(uint2*)(Ptw + (m * 16 + l16) * PSTR + g * 16 + quad * 4) = pw;
      }
    }

    bf16x8 pa[2][2];
#pragma unroll
    for (int m = 0; m < 2; m++) {
      pa[m][0] = *(const bf16x8*)(Ptw + (m * 16 + l16) * PSTR + quad * 8);
      pa[m][1] = *(const bf16x8*)(Ptw + (m * 16 + l16) * PSTR + quad * 8 + 32);
    }

#pragma unroll
    for (int g = 0; g < 4; g++) {
      const unsigned short* vb0 = Vt + (g * 16 + l16) * KTS + quad * 8;
      bf16x8 vf0 = *(const bf16x8*)vb0;
      bf16x8 vf1 = *(const bf16x8*)(vb0 + 32);
#pragma unroll
      for (int m = 0; m < 2; m++) {
        oacc[m][g] = __builtin_amdgcn_mfma_f32_16x16x32_bf16(vf0, pa[m][0], oacc[m][g], 0, 0, 0);
        oacc[m][g] = __builtin_amdgcn_mfma_f32_16x16x32_bf16(vf1, pa[m][1], oacc[m][g], 0, 0, 0);
      }
    }
  }

#pragma unroll
  for (int m = 0; m < 2; m++) {
    float inv = 1.0f / __shfl(oacc[m][3][0], l16);
    size_t obase = ((size_t)b * Nn + q0 + wave * 32 + m * 16 + l16) * Cc + h * HD;
#pragma unroll
    for (int g = 0; g < 3; g++) {
      ushort4 sv;
      sv.x = f2bf(oacc[m][g][0] * inv);
      sv.y = f2bf(oacc[m][g][1] * inv);
      sv.z = f2bf(oacc[m][g][2] * inv);
      sv.w = f2bf(oacc[m][g][3] * inv);
      *(ushort4*)(obh + obase + g * 16 + quad * 4) = sv;
    }
  }
}

// ---------------------------------------------------------------------------
// Kernel F: projection GEMM, 2-term split, async global_load_lds staging
// (same swizzled scheme as qkv_mfma).
// ---------------------------------------------------------------------------
__global__ __launch_bounds__(256, 3) void proj_mfma(
    const unsigned short* __restrict__ pwh, const unsigned short* __restrict__ pwl,
    const unsigned short* __restrict__ obh,
    const float* __restrict__ pb, float* __restrict__ out) {
  __shared__ unsigned short Ash[128 * 64];
  __shared__ unsigned short Asl[128 * 64];
  __shared__ unsigned short Bsh[128 * 64];
  const int b  = blockIdx.z;
  const int c0m = blockIdx.y * 128;
  const int n0 = blockIdx.x * 128;
  const int tid = threadIdx.x;
  const int wave = tid >> 6, lane = tid & 63;
  const int quad = lane >> 4, l16 = lane & 15;
  const int wm = (wave >> 1) * 64, wn = (wave & 1) * 64;

  const int lrow = lane >> 3;
  const int lch  = lane & 7;

  f32x4 acc[4][4];
#pragma unroll
  for (int mi = 0; mi < 4; mi++)
#pragma unroll
    for (int ni = 0; ni < 4; ni++) acc[mi][ni] = (f32x4){0.f, 0.f, 0.f, 0.f};

  const int sw = l16 & 7;

  for (int j0 = 0; j0 < Cc; j0 += 64) {
    __syncthreads();
#pragma unroll
    for (int seg = 0; seg < 4; seg++) {
      int r  = wave * 32 + seg * 8 + lrow;
      int cg = (lch ^ (r & 7)) * 8;
      int lofs = (wave * 32 + seg * 8) * 64;
      size_t gA = (size_t)(c0m + r) * Cc + j0 + cg;
      size_t gB = ((size_t)b * Nn + n0 + r) * Cc + j0 + cg;
      gload_lds16(pwh + gA, &Ash[lofs]);
      gload_lds16(pwl + gA, &Asl[lofs]);
      gload_lds16(obh + gB, &Bsh[lofs]);
    }
    __syncthreads();

#pragma unroll
    for (int ks = 0; ks < 64; ks += 32) {
      const int ach = (((ks >> 3) + quad) ^ sw) * 8;
      bf16x8 ah[4], al[4], bh[4];
#pragma unroll
      for (int mi = 0; mi < 4; mi++) {
        int rowA = (wm + mi * 16 + l16) * 64;
        ah[mi] = *(const bf16x8*)&Ash[rowA + ach];
        al[mi] = *(const bf16x8*)&Asl[rowA + ach];
      }
#pragma unroll
      for (int ni = 0; ni < 4; ni++) {
        int rowB = (wn + ni * 16 + l16) * 64;
        bh[ni] = *(const bf16x8*)&Bsh[rowB + ach];
      }
#pragma unroll
      for (int mi = 0; mi < 4; mi++)
#pragma unroll
        for (int ni = 0; ni < 4; ni++) {
          acc[mi][ni] = __builtin_amdgcn_mfma_f32_16x16x32_bf16(ah[mi], bh[ni], acc[mi][ni], 0, 0, 0);
          acc[mi][ni] = __builtin_amdgcn_mfma_f32_16x16x32_bf16(al[mi], bh[ni], acc[mi][ni], 0, 0, 0);
        }
    }
  }

#pragma unroll
  for (int mi = 0; mi < 4; mi++) {
#pragma unroll
    for (int r = 0; r < 4; r++) {
      int c = c0m + wm + mi * 16 + quad * 4 + r;
      float bv = pb[c];
#pragma unroll
      for (int ni = 0; ni < 4; ni++) {
        int n = n0 + wn + ni * 16 + l16;
        out[((size_t)b * Cc + c) * Nn + n] = acc[mi][ni][r] + bv;
      }
    }
  }
}

// ---------------------------------------------------------------------------
extern "C" void kernel_launch(void* const* d_in, const int* in_sizes, int n_in,
                              void* d_out, int out_size, void* d_ws, size_t ws_size,
                              hipStream_t stream) {
  const float* x     = (const float*)d_in[0];
  const float* temp  = (const float*)d_in[1];
  const float* qkv_w = (const float*)d_in[2];
  const float* qkv_b = (const float*)d_in[3];
  const float* pw    = (const float*)d_in[4];
  const float* pb    = (const float*)d_in[5];
  float* out = (float*)d_out;

  const size_t QKN = (size_t)Bb * NH * Nn * D64;   // 8,388,608
  const size_t WQN = (size_t)C3 * Cc;              // 442,368
  const size_t PWN = (size_t)Cc * Cc;              // 147,456

  unsigned short* Qh  = (unsigned short*)d_ws;
  unsigned short* Kh  = Qh + QKN;
  unsigned short* VhT = Kh + QKN;                  // [B][NH][64][N]
  unsigned short* Wqh = VhT + QKN;
  unsigned short* Wql = Wqh + WQN;
  unsigned short* Pwh = Wql + WQN;
  unsigned short* Pwl = Pwh + PWN;
  unsigned short* Xth = Pwl + PWN;                 // aliased by Obh after qkv
  unsigned short* Obh = Xth;

  prep_kernel<<<3328, 256, 0, stream>>>(qkv_w, pw, Wqh, Wql, Pwh, Pwl, VhT);
  xsplit_kernel<<<dim3(Nn / 64, Cc / 64, Bb), 256, 0, stream>>>(x, Xth);
  qkv_mfma<<<dim3(Nn / 128, C3 / 128, Bb), 256, 0, stream>>>(Wqh, Wql, Xth, qkv_b, Qh, Kh, VhT);
  normqk_kernel<<<(2 * Bb * NH * Nn) / 16, 256, 0, stream>>>(Qh, Kh);
  attn_mfma<<<1024, 256, 0, stream>>>(Qh, Kh, VhT, temp, Obh);
  proj_mfma<<<dim3(Nn / 128, Cc / 128, Bb), 256, 0, stream>>>(Pwh, Pwl, Obh, pb, out);
}

// Round 8
// 213.968 us; speedup vs baseline: 1.5641x; 1.0349x over previous
//
#include <hip/hip_runtime.h>
#include <hip/hip_bf16.h>

// Problem constants
#define Bb   16
#define Cc   384
#define Nn   1024
#define NH   8
#define HD   48
#define C3   1152
#define D64  64          // padded head dim for MFMA
#define KTS  72          // LDS row stride (ushorts) for attn K/V tiles
#define PSTR 72          // LDS row stride for attn P tile

typedef _Float16 f16x8 __attribute__((ext_vector_type(8)));
typedef float    f32x4 __attribute__((ext_vector_type(4)));
typedef unsigned short ushort8 __attribute__((ext_vector_type(8)));

__device__ inline unsigned short f2h(float f) {
  union { _Float16 h; unsigned short u; } cv;
  cv.h = (_Float16)f;            // v_cvt_f16_f32, RNE
  return cv.u;
}
__device__ inline float h2f(unsigned short s) {
  union { _Float16 h; unsigned short u; } cv;
  cv.u = s;
  return (float)cv.h;
}
__device__ inline unsigned int packh(float a, float b) {
  return (unsigned int)f2h(a) | ((unsigned int)f2h(b) << 16);
}

// async 16B global->LDS (no VGPR round-trip). lds dest = wave-uniform base
// + lane*16; all lanes must pass the same lds base.
__device__ inline void gload_lds16(const unsigned short* g, unsigned short* l) {
  __builtin_amdgcn_global_load_lds(
      (const __attribute__((address_space(1))) void*)g,
      (__attribute__((address_space(3))) void*)l, 16, 0, 0);
}

// ---------------------------------------------------------------------------
// Kernel A: prep — weights fp32 -> f16, VhT pad rows (48=ones f16, 49..63=0).
// ---------------------------------------------------------------------------
__global__ __launch_bounds__(256) void prep_kernel(
    const float* __restrict__ qkv_w, const float* __restrict__ pw,
    unsigned short* __restrict__ wqh, unsigned short* __restrict__ pwh,
    unsigned short* __restrict__ vt) {
  const int bid = blockIdx.x;
  if (bid < 1728) {
    int i = bid * 256 + threadIdx.x;
    wqh[i] = f2h(qkv_w[i]);
  } else if (bid < 2304) {
    int i = (bid - 1728) * 256 + threadIdx.x;
    pwh[i] = f2h(pw[i]);
  } else {
    int idx8 = (bid - 2304) * 256 + threadIdx.x;   // 262144 ushort8 chunks
    int bh = idx8 >> 11;
    int rem = idx8 & 2047;
    int row = 48 + (rem >> 7);
    int col = (rem & 127) * 8;
    unsigned short fill = (row == 48) ? (unsigned short)0x3C00 : (unsigned short)0;
    ushort8 v;
#pragma unroll
    for (int j = 0; j < 8; j++) v[j] = fill;
    *(ushort8*)(vt + (size_t)bh * D64 * Nn + (size_t)row * Nn + col) = v;
  }
}

// ---------------------------------------------------------------------------
// Kernel B: x [B][C][N] fp32 -> xT [B][N][C] f16 (transpose + convert).
// ---------------------------------------------------------------------------
__global__ __launch_bounds__(256) void xsplit_kernel(
    const float* __restrict__ x, unsigned short* __restrict__ xh) {
  __shared__ float tile[64][65];
  const int b  = blockIdx.z;
  const int c0 = blockIdx.y * 64;
  const int n0 = blockIdx.x * 64;
  const int t  = threadIdx.x;
  const int rl = t >> 2, sc = (t & 3) * 16;
  {
    const float* src = x + ((size_t)b * Cc + c0 + rl) * Nn + n0 + sc;
#pragma unroll
    for (int i = 0; i < 4; i++) {
      float4 v = *(const float4*)(src + i * 4);
      tile[rl][sc + i * 4 + 0] = v.x; tile[rl][sc + i * 4 + 1] = v.y;
      tile[rl][sc + i * 4 + 2] = v.z; tile[rl][sc + i * 4 + 3] = v.w;
    }
  }
  __syncthreads();
  {
    ushort8 h0, h1;
#pragma unroll
    for (int i = 0; i < 8; i++) h0[i] = f2h(tile[sc + i][rl]);
#pragma unroll
    for (int i = 0; i < 8; i++) h1[i] = f2h(tile[sc + 8 + i][rl]);
    size_t dst = ((size_t)b * Nn + n0 + rl) * Cc + c0 + sc;
    *(ushort8*)(xh + dst) = h0; *(ushort8*)(xh + dst + 8) = h1;
  }
}

// ---------------------------------------------------------------------------
// Kernel C: QKV GEMM, f16 MFMA single-term, async global_load_lds staging.
// LDS tiles 128x64 f16, no pad; XOR swizzle chunk' = chunk ^ (row&7).
// 32 KB LDS -> 5 blocks/CU.
// ---------------------------------------------------------------------------
__global__ __launch_bounds__(256, 4) void qkv_mfma(
    const unsigned short* __restrict__ wh,
    const unsigned short* __restrict__ xh,
    const float* __restrict__ bias,
    unsigned short* __restrict__ qh, unsigned short* __restrict__ kh,
    unsigned short* __restrict__ vt) {
  __shared__ unsigned short Ash[128 * 64];
  __shared__ unsigned short Bsh[128 * 64];
  const int b  = blockIdx.z;
  const int j0 = blockIdx.y * 128;
  const int n0 = blockIdx.x * 128;
  const int tid = threadIdx.x;
  const int wave = tid >> 6, lane = tid & 63;
  const int quad = lane >> 4, l16 = lane & 15;
  const int wm = (wave >> 1) * 64, wn = (wave & 1) * 64;

  const int lrow = lane >> 3;    // staging row within 8-row segment
  const int lch  = lane & 7;     // staging chunk (16B units)

  f32x4 acc[4][4];
#pragma unroll
  for (int mi = 0; mi < 4; mi++)
#pragma unroll
    for (int ni = 0; ni < 4; ni++) acc[mi][ni] = (f32x4){0.f, 0.f, 0.f, 0.f};

  const int sw = l16 & 7;        // fragment-read swizzle

  for (int c0 = 0; c0 < Cc; c0 += 64) {
    __syncthreads();
#pragma unroll
    for (int seg = 0; seg < 4; seg++) {
      int r  = wave * 32 + seg * 8 + lrow;          // tile row 0..127
      int cg = (lch ^ (r & 7)) * 8;                 // swizzled global chunk
      int lofs = (wave * 32 + seg * 8) * 64;        // wave-uniform seg base
      size_t gA = (size_t)(j0 + r) * Cc + c0 + cg;
      size_t gB = ((size_t)b * Nn + n0 + r) * Cc + c0 + cg;
      gload_lds16(wh + gA, &Ash[lofs]);
      gload_lds16(xh + gB, &Bsh[lofs]);
    }
    __syncthreads();

#pragma unroll
    for (int ks = 0; ks < 64; ks += 32) {
      const int ach = (((ks >> 3) + quad) ^ sw) * 8;   // de-swizzled column
      f16x8 ah[4], bh[4];
#pragma unroll
      for (int mi = 0; mi < 4; mi++) {
        int rowA = (wm + mi * 16 + l16) * 64;
        ah[mi] = *(const f16x8*)&Ash[rowA + ach];
      }
#pragma unroll
      for (int ni = 0; ni < 4; ni++) {
        int rowB = (wn + ni * 16 + l16) * 64;
        bh[ni] = *(const f16x8*)&Bsh[rowB + ach];
      }
#pragma unroll
      for (int mi = 0; mi < 4; mi++)
#pragma unroll
        for (int ni = 0; ni < 4; ni++)
          acc[mi][ni] = __builtin_amdgcn_mfma_f32_16x16x32_f16(ah[mi], bh[ni], acc[mi][ni], 0, 0, 0);
    }
  }

  const int part = (j0 >= 768) ? 2 : (j0 >= 384 ? 1 : 0);
  unsigned short* dstq = (part == 0) ? qh : kh;
#pragma unroll
  for (int mi = 0; mi < 4; mi++) {
#pragma unroll
    for (int r = 0; r < 4; r++) {
      int j = j0 + wm + mi * 16 + quad * 4 + r;
      int jl = j - part * Cc;
      int h = jl / HD, d = jl % HD;
      float bv = bias[j];
      if (part < 2) {
#pragma unroll
        for (int ni = 0; ni < 4; ni++) {
          int n = n0 + wn + ni * 16 + l16;
          dstq[((size_t)(b * NH + h) * Nn + n) * D64 + d] = f2h(acc[mi][ni][r] + bv);
        }
      } else {
        unsigned short* vrow = vt + ((size_t)(b * NH + h) * D64 + d) * Nn;
#pragma unroll
        for (int ni = 0; ni < 4; ni++) {
          int n = n0 + wn + ni * 16 + l16;
          vrow[n] = f2h(acc[mi][ni][r] + bv);
        }
      }
    }
  }
}

// ---------------------------------------------------------------------------
// Kernel D: in-place L2 norm of q,k rows (f16) + zero dim pads 48..63.
// ---------------------------------------------------------------------------
__global__ __launch_bounds__(256) void normqk_kernel(
    unsigned short* __restrict__ qh, unsigned short* __restrict__ kh) {
  const int tid = threadIdx.x;
  const int row = blockIdx.x * 16 + (tid >> 4);
  const int l16 = tid & 15;
  const int TOT = Bb * NH * Nn;
  unsigned short* buf = (row < TOT) ? qh : kh;
  int r = (row < TOT) ? row : row - TOT;
  unsigned short* rowb = buf + (size_t)r * D64;
  unsigned short* p = rowb + l16 * 3;
  float a = h2f(p[0]), b = h2f(p[1]), c = h2f(p[2]);
  float ss = a * a + b * b + c * c;
  ss += __shfl_xor(ss, 1, 16);
  ss += __shfl_xor(ss, 2, 16);
  ss += __shfl_xor(ss, 4, 16);
  ss += __shfl_xor(ss, 8, 16);
  float scale = 1.0f / fmaxf(sqrtf(ss), 1e-12f);
  p[0] = f2h(a * scale); p[1] = f2h(b * scale); p[2] = f2h(c * scale);
  if (l16 < 8) ((unsigned int*)(rowb + HD))[l16] = 0u;
}

// ---------------------------------------------------------------------------
// Kernel E: f16 MFMA flash attention (transposed path + SW pipeline + XCD
// swizzle).  Static max M=|T|; denominator via ones-column of V^T.
// ---------------------------------------------------------------------------
__global__ __launch_bounds__(256, 4) void attn_mfma(
    const unsigned short* __restrict__ qh, const unsigned short* __restrict__ kh,
    const unsigned short* __restrict__ vt, const float* __restrict__ temp,
    unsigned short* __restrict__ obh) {
  __shared__ unsigned short Kt[64 * KTS];
  __shared__ unsigned short Vt[64 * KTS];
  __shared__ unsigned short Pt[4 * 32 * PSTR];

  const int bid = blockIdx.x;
  const int hb = bid & 127;
  const int q0 = (bid >> 7) * 128;
  const int b = hb >> 3, h = hb & 7;
  const int tid = threadIdx.x;
  const int wave = tid >> 6, lane = tid & 63;
  const int quad = lane >> 4, l16 = lane & 15;

  const size_t headQ = ((size_t)(b * NH + h) * Nn) * D64;
  const unsigned short* Qg = qh + headQ + (size_t)(q0 + wave * 32) * D64;
  const unsigned short* Kg = kh + headQ;
  const unsigned short* Vg = vt + ((size_t)(b * NH + h) * D64) * Nn;

  f16x8 qa0[2], qa1[2];
#pragma unroll
  for (int m = 0; m < 2; m++) {
    qa0[m] = *(const f16x8*)(Qg + (m * 16 + l16) * D64 + quad * 8);
    qa1[m] = *(const f16x8*)(Qg + (m * 16 + l16) * D64 + quad * 8 + 32);
  }

  const float T2 = temp[h] * 1.44269504f;
  const float M2 = fabsf(T2);

  f32x4 oacc[2][4];
#pragma unroll
  for (int m = 0; m < 2; m++)
#pragma unroll
    for (int g = 0; g < 4; g++) oacc[m][g] = (f32x4){0.f, 0.f, 0.f, 0.f};
  const f32x4 zf = (f32x4){0.f, 0.f, 0.f, 0.f};

  unsigned short* Ptw = Pt + wave * 32 * PSTR;
  const int skey = tid >> 2;
  const int spart = (tid & 3) * 16;

  const unsigned short* ksrc = Kg + (size_t)skey * D64 + spart;
  const unsigned short* vsrc = Vg + (size_t)skey * Nn + spart;
  unsigned short* kdst = Kt + skey * KTS + spart;
  unsigned short* vdst = Vt + skey * KTS + spart;

  uint4 kr0 = *(const uint4*)(ksrc);
  uint4 kr1 = *(const uint4*)(ksrc + 8);
  uint4 vr0 = *(const uint4*)(vsrc);
  uint4 vr1 = *(const uint4*)(vsrc + 8);

  for (int kt = 0; kt < Nn / 64; kt++) {
    __syncthreads();
    *(uint4*)kdst = kr0;
    *(uint4*)(kdst + 8) = kr1;
    *(uint4*)vdst = vr0;
    *(uint4*)(vdst + 8) = vr1;
    __syncthreads();

    if (kt < Nn / 64 - 1) {
      const unsigned short* kn = ksrc + (size_t)(kt + 1) * 64 * D64;
      const unsigned short* vn = vsrc + (size_t)(kt + 1) * 64;
      kr0 = *(const uint4*)kn;
      kr1 = *(const uint4*)(kn + 8);
      vr0 = *(const uint4*)vn;
      vr1 = *(const uint4*)(vn + 8);
    }

    f32x4 sT[2][4];
#pragma unroll
    for (int g = 0; g < 4; g++) {
      const unsigned short* kb = Kt + (g * 16 + l16) * KTS + quad * 8;
      f16x8 kf0 = *(const f16x8*)kb;
      f16x8 kf1 = *(const f16x8*)(kb + 32);
#pragma unroll
      for (int m = 0; m < 2; m++) {
        f32x4 s = __builtin_amdgcn_mfma_f32_16x16x32_f16(kf0, qa0[m], zf, 0, 0, 0);
        sT[m][g] = __builtin_amdgcn_mfma_f32_16x16x32_f16(kf1, qa1[m], s, 0, 0, 0);
      }
    }

#pragma unroll
    for (int m = 0; m < 2; m++) {
#pragma unroll
      for (int g = 0; g < 4; g++) {
        uint2 pw;
        pw.x = packh(__builtin_amdgcn_exp2f(sT[m][g][0] * T2 - M2),
                     __builtin_amdgcn_exp2f(sT[m][g][1] * T2 - M2));
        pw.y = packh(__builtin_amdgcn_exp2f(sT[m][g][2] * T2 - M2),
                     __builtin_amdgcn_exp2f(sT[m][g][3] * T2 - M2));
        *(uint2*)(Ptw + (m * 16 + l16) * PSTR + g * 16 + quad * 4) = pw;
      }
    }

    f16x8 pa[2][2];
#pragma unroll
    for (int m = 0; m < 2; m++) {
      pa[m][0] = *(const f16x8*)(Ptw + (m * 16 + l16) * PSTR + quad * 8);
      pa[m][1] = *(const f16x8*)(Ptw + (m * 16 + l16) * PSTR + quad * 8 + 32);
    }

#pragma unroll
    for (int g = 0; g < 4; g++) {
      const unsigned short* vb0 = Vt + (g * 16 + l16) * KTS + quad * 8;
      f16x8 vf0 = *(const f16x8*)vb0;
      f16x8 vf1 = *(const f16x8*)(vb0 + 32);
#pragma unroll
      for (int m = 0; m < 2; m++) {
        oacc[m][g] = __builtin_amdgcn_mfma_f32_16x16x32_f16(vf0, pa[m][0], oacc[m][g], 0, 0, 0);
        oacc[m][g] = __builtin_amdgcn_mfma_f32_16x16x32_f16(vf1, pa[m][1], oacc[m][g], 0, 0, 0);
      }
    }
  }

#pragma unroll
  for (int m = 0; m < 2; m++) {
    float inv = 1.0f / __shfl(oacc[m][3][0], l16);
    size_t obase = ((size_t)b * Nn + q0 + wave * 32 + m * 16 + l16) * Cc + h * HD;
#pragma unroll
    for (int g = 0; g < 3; g++) {
      ushort4 sv;
      sv.x = f2h(oacc[m][g][0] * inv);
      sv.y = f2h(oacc[m][g][1] * inv);
      sv.z = f2h(oacc[m][g][2] * inv);
      sv.w = f2h(oacc[m][g][3] * inv);
      *(ushort4*)(obh + obase + g * 16 + quad * 4) = sv;
    }
  }
}

// ---------------------------------------------------------------------------
// Kernel F: projection GEMM, f16 single-term, async global_load_lds staging.
// ---------------------------------------------------------------------------
__global__ __launch_bounds__(256, 4) void proj_mfma(
    const unsigned short* __restrict__ pwh,
    const unsigned short* __restrict__ obh,
    const float* __restrict__ pb, float* __restrict__ out) {
  __shared__ unsigned short Ash[128 * 64];
  __shared__ unsigned short Bsh[128 * 64];
  const int b  = blockIdx.z;
  const int c0m = blockIdx.y * 128;
  const int n0 = blockIdx.x * 128;
  const int tid = threadIdx.x;
  const int wave = tid >> 6, lane = tid & 63;
  const int quad = lane >> 4, l16 = lane & 15;
  const int wm = (wave >> 1) * 64, wn = (wave & 1) * 64;

  const int lrow = lane >> 3;
  const int lch  = lane & 7;

  f32x4 acc[4][4];
#pragma unroll
  for (int mi = 0; mi < 4; mi++)
#pragma unroll
    for (int ni = 0; ni < 4; ni++) acc[mi][ni] = (f32x4){0.f, 0.f, 0.f, 0.f};

  const int sw = l16 & 7;

  for (int j0 = 0; j0 < Cc; j0 += 64) {
    __syncthreads();
#pragma unroll
    for (int seg = 0; seg < 4; seg++) {
      int r  = wave * 32 + seg * 8 + lrow;
      int cg = (lch ^ (r & 7)) * 8;
      int lofs = (wave * 32 + seg * 8) * 64;
      size_t gA = (size_t)(c0m + r) * Cc + j0 + cg;
      size_t gB = ((size_t)b * Nn + n0 + r) * Cc + j0 + cg;
      gload_lds16(pwh + gA, &Ash[lofs]);
      gload_lds16(obh + gB, &Bsh[lofs]);
    }
    __syncthreads();

#pragma unroll
    for (int ks = 0; ks < 64; ks += 32) {
      const int ach = (((ks >> 3) + quad) ^ sw) * 8;
      f16x8 ah[4], bh[4];
#pragma unroll
      for (int mi = 0; mi < 4; mi++) {
        int rowA = (wm + mi * 16 + l16) * 64;
        ah[mi] = *(const f16x8*)&Ash[rowA + ach];
      }
#pragma unroll
      for (int ni = 0; ni < 4; ni++) {
        int rowB = (wn + ni * 16 + l16) * 64;
        bh[ni] = *(const f16x8*)&Bsh[rowB + ach];
      }
#pragma unroll
      for (int mi = 0; mi < 4; mi++)
#pragma unroll
        for (int ni = 0; ni < 4; ni++)
          acc[mi][ni] = __builtin_amdgcn_mfma_f32_16x16x32_f16(ah[mi], bh[ni], acc[mi][ni], 0, 0, 0);
    }
  }

#pragma unroll
  for (int mi = 0; mi < 4; mi++) {
#pragma unroll
    for (int r = 0; r < 4; r++) {
      int c = c0m + wm + mi * 16 + quad * 4 + r;
      float bv = pb[c];
#pragma unroll
      for (int ni = 0; ni < 4; ni++) {
        int n = n0 + wn + ni * 16 + l16;
        out[((size_t)b * Cc + c) * Nn + n] = acc[mi][ni][r] + bv;
      }
    }
  }
}

// ---------------------------------------------------------------------------
extern "C" void kernel_launch(void* const* d_in, const int* in_sizes, int n_in,
                              void* d_out, int out_size, void* d_ws, size_t ws_size,
                              hipStream_t stream) {
  const float* x     = (const float*)d_in[0];
  const float* temp  = (const float*)d_in[1];
  const float* qkv_w = (const float*)d_in[2];
  const float* qkv_b = (const float*)d_in[3];
  const float* pw    = (const float*)d_in[4];
  const float* pb    = (const float*)d_in[5];
  float* out = (float*)d_out;

  const size_t QKN = (size_t)Bb * NH * Nn * D64;   // 8,388,608
  const size_t WQN = (size_t)C3 * Cc;              // 442,368
  const size_t PWN = (size_t)Cc * Cc;              // 147,456

  unsigned short* Qh  = (unsigned short*)d_ws;
  unsigned short* Kh  = Qh + QKN;
  unsigned short* VhT = Kh + QKN;                  // [B][NH][64][N]
  unsigned short* Wqh = VhT + QKN;
  unsigned short* Pwh = Wqh + WQN;
  unsigned short* Xth = Pwh + PWN;                 // aliased by Obh after qkv
  unsigned short* Obh = Xth;

  prep_kernel<<<3328, 256, 0, stream>>>(qkv_w, pw, Wqh, Pwh, VhT);
  xsplit_kernel<<<dim3(Nn / 64, Cc / 64, Bb), 256, 0, stream>>>(x, Xth);
  qkv_mfma<<<dim3(Nn / 128, C3 / 128, Bb), 256, 0, stream>>>(Wqh, Xth, qkv_b, Qh, Kh, VhT);
  normqk_kernel<<<(2 * Bb * NH * Nn) / 16, 256, 0, stream>>>(Qh, Kh);
  attn_mfma<<<1024, 256, 0, stream>>>(Qh, Kh, VhT, temp, Obh);
  proj_mfma<<<dim3(Nn / 128, Cc / 128, Bb), 256, 0, stream>>>(Pwh, Obh, pb, out);
}

// Round 9
// 165.702 us; speedup vs baseline: 2.0198x; 1.2913x over previous
//
#include <hip/hip_runtime.h>
#include <hip/hip_bf16.h>

// Problem constants
#define Bb   16
#define Cc   384
#define Nn   1024
#define NH   8
#define HD   48
#define C3   1152
#define D64  64          // padded head dim for MFMA
#define KTS  72          // LDS row stride (ushorts) for attn K/V tiles
#define PSTR 72          // LDS row stride for attn P tile

typedef _Float16 f16x8 __attribute__((ext_vector_type(8)));
typedef float    f32x4 __attribute__((ext_vector_type(4)));
typedef unsigned short ushort8 __attribute__((ext_vector_type(8)));

__device__ inline unsigned short f2h(float f) {
  union { _Float16 h; unsigned short u; } cv;
  cv.h = (_Float16)f;            // v_cvt_f16_f32, RNE
  return cv.u;
}
__device__ inline float h2f(unsigned short s) {
  union { _Float16 h; unsigned short u; } cv;
  cv.u = s;
  return (float)cv.h;
}
__device__ inline unsigned int packh(float a, float b) {
  return (unsigned int)f2h(a) | ((unsigned int)f2h(b) << 16);
}

// async 16B global->LDS; lds dest = wave-uniform base + lane*16.
__device__ inline void gload_lds16(const unsigned short* g, unsigned short* l) {
  __builtin_amdgcn_global_load_lds(
      (const __attribute__((address_space(1))) void*)g,
      (__attribute__((address_space(3))) void*)l, 16, 0, 0);
}

// ---------------------------------------------------------------------------
// Kernel A: prep — weights fp32 -> f16, VhT pad rows (48=ones f16, 49..63=0).
// ---------------------------------------------------------------------------
__global__ __launch_bounds__(256) void prep_kernel(
    const float* __restrict__ qkv_w, const float* __restrict__ pw,
    unsigned short* __restrict__ wqh, unsigned short* __restrict__ pwh,
    unsigned short* __restrict__ vt) {
  const int bid = blockIdx.x;
  if (bid < 1728) {
    int i = bid * 256 + threadIdx.x;
    wqh[i] = f2h(qkv_w[i]);
  } else if (bid < 2304) {
    int i = (bid - 1728) * 256 + threadIdx.x;
    pwh[i] = f2h(pw[i]);
  } else {
    int idx8 = (bid - 2304) * 256 + threadIdx.x;   // 262144 ushort8 chunks
    int bh = idx8 >> 11;
    int rem = idx8 & 2047;
    int row = 48 + (rem >> 7);
    int col = (rem & 127) * 8;
    unsigned short fill = (row == 48) ? (unsigned short)0x3C00 : (unsigned short)0;
    ushort8 v;
#pragma unroll
    for (int j = 0; j < 8; j++) v[j] = fill;
    *(ushort8*)(vt + (size_t)bh * D64 * Nn + (size_t)row * Nn + col) = v;
  }
}

// ---------------------------------------------------------------------------
// Kernel B: x [B][C][N] fp32 -> xT [B][N][C] f16 (transpose + convert).
// ---------------------------------------------------------------------------
__global__ __launch_bounds__(256) void xsplit_kernel(
    const float* __restrict__ x, unsigned short* __restrict__ xh) {
  __shared__ float tile[64][65];
  const int b  = blockIdx.z;
  const int c0 = blockIdx.y * 64;
  const int n0 = blockIdx.x * 64;
  const int t  = threadIdx.x;
  const int rl = t >> 2, sc = (t & 3) * 16;
  {
    const float* src = x + ((size_t)b * Cc + c0 + rl) * Nn + n0 + sc;
#pragma unroll
    for (int i = 0; i < 4; i++) {
      float4 v = *(const float4*)(src + i * 4);
      tile[rl][sc + i * 4 + 0] = v.x; tile[rl][sc + i * 4 + 1] = v.y;
      tile[rl][sc + i * 4 + 2] = v.z; tile[rl][sc + i * 4 + 3] = v.w;
    }
  }
  __syncthreads();
  {
    ushort8 h0, h1;
#pragma unroll
    for (int i = 0; i < 8; i++) h0[i] = f2h(tile[sc + i][rl]);
#pragma unroll
    for (int i = 0; i < 8; i++) h1[i] = f2h(tile[sc + 8 + i][rl]);
    size_t dst = ((size_t)b * Nn + n0 + rl) * Cc + c0 + sc;
    *(ushort8*)(xh + dst) = h0; *(ushort8*)(xh + dst + 8) = h1;
  }
}

// ---------------------------------------------------------------------------
// Kernel C: QKV GEMM, f16 MFMA, j-tile = 96 = exactly 2 heads.
//  - async global_load_lds staging, XOR-swizzled, no pad.
//  - q/k: L2 norm FUSED in epilogue (fp32, pre-rounding), then LDS transpose
//    -> full-128B-line coalesced stores incl. zeroed pads (normqk deleted).
//  - v: direct V^T stores (32B-sector aligned).
// ---------------------------------------------------------------------------
__global__ __launch_bounds__(256, 4) void qkv_mfma(
    const unsigned short* __restrict__ wh,
    const unsigned short* __restrict__ xh,
    const float* __restrict__ bias,
    unsigned short* __restrict__ qh, unsigned short* __restrict__ kh,
    unsigned short* __restrict__ vt) {
  // staging: A 96x64 (6144 us) + B 128x64 (8192 us) = 14336 us
  // epilogue transpose: T 128x136 = 17408 us  -> array = 17408 us (34 KB)
  __shared__ unsigned short lds[128 * 136];
  unsigned short* Ash = lds;          // [96][64]
  unsigned short* Bsh = lds + 6144;   // [128][64]

  const int b  = blockIdx.z;
  const int yb = blockIdx.y;
  const int j0 = yb * 96;
  const int n0 = blockIdx.x * 128;
  const int tid = threadIdx.x;
  const int wave = tid >> 6, lane = tid & 63;
  const int quad = lane >> 4, l16 = lane & 15;
  const int wm = (wave >> 1) * 48, wn = (wave & 1) * 64;
  const int hs = wave >> 1;           // head-sub within the 2-head tile

  f32x4 acc[3][4];
#pragma unroll
  for (int mi = 0; mi < 3; mi++)
#pragma unroll
    for (int ni = 0; ni < 4; ni++) acc[mi][ni] = (f32x4){0.f, 0.f, 0.f, 0.f};

  const int sw = l16 & 7;

  for (int c0 = 0; c0 < Cc; c0 += 64) {
    __syncthreads();
    // stage A: 96 rows, 3 rounds of 32 rows (4 waves x 8 rows)
#pragma unroll
    for (int s = 0; s < 3; s++) {
      int r  = s * 32 + wave * 8 + (lane >> 3);
      int cg = ((lane & 7) ^ (lane >> 3)) * 8;
      gload_lds16(wh + (size_t)(j0 + r) * Cc + c0 + cg,
                  &Ash[(s * 32 + wave * 8) * 64]);
    }
    // stage B: 128 rows, 4 rounds
#pragma unroll
    for (int s = 0; s < 4; s++) {
      int r  = s * 32 + wave * 8 + (lane >> 3);
      int cg = ((lane & 7) ^ (lane >> 3)) * 8;
      gload_lds16(xh + ((size_t)b * Nn + n0 + r) * Cc + c0 + cg,
                  &Bsh[(s * 32 + wave * 8) * 64]);
    }
    __syncthreads();

#pragma unroll
    for (int ks = 0; ks < 64; ks += 32) {
      const int ach = (((ks >> 3) + quad) ^ sw) * 8;
      f16x8 ah[3], bh[4];
#pragma unroll
      for (int mi = 0; mi < 3; mi++)
        ah[mi] = *(const f16x8*)&Ash[(wm + mi * 16 + l16) * 64 + ach];
#pragma unroll
      for (int ni = 0; ni < 4; ni++)
        bh[ni] = *(const f16x8*)&Bsh[(wn + ni * 16 + l16) * 64 + ach];
#pragma unroll
      for (int mi = 0; mi < 3; mi++)
#pragma unroll
        for (int ni = 0; ni < 4; ni++)
          acc[mi][ni] = __builtin_amdgcn_mfma_f32_16x16x32_f16(ah[mi], bh[ni], acc[mi][ni], 0, 0, 0);
    }
  }

  const int part = yb >> 2;           // 0=q, 1=k, 2=v
  const int tq   = yb & 3;            // tile within part -> heads 2tq, 2tq+1
  float bv[3][4];
#pragma unroll
  for (int mi = 0; mi < 3; mi++)
#pragma unroll
    for (int r = 0; r < 4; r++)
      bv[mi][r] = bias[j0 + wm + mi * 16 + quad * 4 + r];

  if (part < 2) {
    unsigned short* dst = part ? kh : qh;
    __syncthreads();   // lds reuse: staging -> transpose buffer
#pragma unroll
    for (int ni = 0; ni < 4; ni++) {
      float vals[3][4];
      float ss = 0.f;
#pragma unroll
      for (int mi = 0; mi < 3; mi++)
#pragma unroll
        for (int r = 0; r < 4; r++) {
          float v = acc[mi][ni][r] + bv[mi][r];
          vals[mi][r] = v; ss += v * v;
        }
      ss += __shfl_xor(ss, 16);       // sum the 4 quads -> full 48-d row norm
      ss += __shfl_xor(ss, 32);
      float scale = 1.0f / fmaxf(sqrtf(ss), 1e-12f);
      int n = wn + ni * 16 + l16;
#pragma unroll
      for (int mi = 0; mi < 3; mi++) {
        ushort4 sv;
        sv.x = f2h(vals[mi][0] * scale);
        sv.y = f2h(vals[mi][1] * scale);
        sv.z = f2h(vals[mi][2] * scale);
        sv.w = f2h(vals[mi][3] * scale);
        *(ushort4*)&lds[n * 136 + hs * 64 + mi * 16 + quad * 4] = sv;
      }
    }
    {  // zero the d=48..63 pads (full-line stores below include them)
      int n = tid >> 1, h2 = tid & 1;
      ushort8 z = {0, 0, 0, 0, 0, 0, 0, 0};
      *(ushort8*)&lds[n * 136 + h2 * 64 + 48] = z;
      *(ushort8*)&lds[n * 136 + h2 * 64 + 56] = z;
    }
    __syncthreads();
    // coalesced store: per instr 4 n-rows x 2 heads x 128B full lines
#pragma unroll
    for (int it = 0; it < 8; it++) {
      int n = wave * 32 + it * 4 + (lane >> 4);
      int chunk = lane & 15;
      int hs3 = chunk >> 3, c8 = (chunk & 7) * 8;
      int h = 2 * tq + hs3;
      ushort8 v = *(const ushort8*)&lds[n * 136 + hs3 * 64 + c8];
      *(ushort8*)(dst + ((size_t)(b * NH + h) * Nn + n0 + n) * D64 + c8) = v;
    }
  } else {
    // V^T [B][NH][64][N]: lane-contiguous n, 32B-sector aligned
    const int h = 2 * tq + hs;
#pragma unroll
    for (int mi = 0; mi < 3; mi++) {
#pragma unroll
      for (int r = 0; r < 4; r++) {
        int d = mi * 16 + quad * 4 + r;
        unsigned short* vrow = vt + ((size_t)(b * NH + h) * D64 + d) * Nn;
#pragma unroll
        for (int ni = 0; ni < 4; ni++) {
          int n = n0 + wn + ni * 16 + l16;
          vrow[n] = f2h(acc[mi][ni][r] + bv[mi][r]);
        }
      }
    }
  }
}

// ---------------------------------------------------------------------------
// Kernel E: f16 MFMA flash attention (transposed path + SW pipeline + XCD
// swizzle).  Static max M=|T|; denominator via ones-column of V^T.
// ---------------------------------------------------------------------------
__global__ __launch_bounds__(256, 4) void attn_mfma(
    const unsigned short* __restrict__ qh, const unsigned short* __restrict__ kh,
    const unsigned short* __restrict__ vt, const float* __restrict__ temp,
    unsigned short* __restrict__ obh) {
  __shared__ unsigned short Kt[64 * KTS];
  __shared__ unsigned short Vt[64 * KTS];
  __shared__ unsigned short Pt[4 * 32 * PSTR];

  const int bid = blockIdx.x;
  const int hb = bid & 127;
  const int q0 = (bid >> 7) * 128;
  const int b = hb >> 3, h = hb & 7;
  const int tid = threadIdx.x;
  const int wave = tid >> 6, lane = tid & 63;
  const int quad = lane >> 4, l16 = lane & 15;

  const size_t headQ = ((size_t)(b * NH + h) * Nn) * D64;
  const unsigned short* Qg = qh + headQ + (size_t)(q0 + wave * 32) * D64;
  const unsigned short* Kg = kh + headQ;
  const unsigned short* Vg = vt + ((size_t)(b * NH + h) * D64) * Nn;

  f16x8 qa0[2], qa1[2];
#pragma unroll
  for (int m = 0; m < 2; m++) {
    qa0[m] = *(const f16x8*)(Qg + (m * 16 + l16) * D64 + quad * 8);
    qa1[m] = *(const f16x8*)(Qg + (m * 16 + l16) * D64 + quad * 8 + 32);
  }

  const float T2 = temp[h] * 1.44269504f;
  const float M2 = fabsf(T2);

  f32x4 oacc[2][4];
#pragma unroll
  for (int m = 0; m < 2; m++)
#pragma unroll
    for (int g = 0; g < 4; g++) oacc[m][g] = (f32x4){0.f, 0.f, 0.f, 0.f};
  const f32x4 zf = (f32x4){0.f, 0.f, 0.f, 0.f};

  unsigned short* Ptw = Pt + wave * 32 * PSTR;
  const int skey = tid >> 2;
  const int spart = (tid & 3) * 16;

  const unsigned short* ksrc = Kg + (size_t)skey * D64 + spart;
  const unsigned short* vsrc = Vg + (size_t)skey * Nn + spart;
  unsigned short* kdst = Kt + skey * KTS + spart;
  unsigned short* vdst = Vt + skey * KTS + spart;

  uint4 kr0 = *(const uint4*)(ksrc);
  uint4 kr1 = *(const uint4*)(ksrc + 8);
  uint4 vr0 = *(const uint4*)(vsrc);
  uint4 vr1 = *(const uint4*)(vsrc + 8);

  for (int kt = 0; kt < Nn / 64; kt++) {
    __syncthreads();
    *(uint4*)kdst = kr0;
    *(uint4*)(kdst + 8) = kr1;
    *(uint4*)vdst = vr0;
    *(uint4*)(vdst + 8) = vr1;
    __syncthreads();

    if (kt < Nn / 64 - 1) {
      const unsigned short* kn = ksrc + (size_t)(kt + 1) * 64 * D64;
      const unsigned short* vn = vsrc + (size_t)(kt + 1) * 64;
      kr0 = *(const uint4*)kn;
      kr1 = *(const uint4*)(kn + 8);
      vr0 = *(const uint4*)vn;
      vr1 = *(const uint4*)(vn + 8);
    }

    f32x4 sT[2][4];
#pragma unroll
    for (int g = 0; g < 4; g++) {
      const unsigned short* kb = Kt + (g * 16 + l16) * KTS + quad * 8;
      f16x8 kf0 = *(const f16x8*)kb;
      f16x8 kf1 = *(const f16x8*)(kb + 32);
#pragma unroll
      for (int m = 0; m < 2; m++) {
        f32x4 s = __builtin_amdgcn_mfma_f32_16x16x32_f16(kf0, qa0[m], zf, 0, 0, 0);
        sT[m][g] = __builtin_amdgcn_mfma_f32_16x16x32_f16(kf1, qa1[m], s, 0, 0, 0);
      }
    }

#pragma unroll
    for (int m = 0; m < 2; m++) {
#pragma unroll
      for (int g = 0; g < 4; g++) {
        uint2 pw;
        pw.x = packh(__builtin_amdgcn_exp2f(sT[m][g][0] * T2 - M2),
                     __builtin_amdgcn_exp2f(sT[m][g][1] * T2 - M2));
        pw.y = packh(__builtin_amdgcn_exp2f(sT[m][g][2] * T2 - M2),
                     __builtin_amdgcn_exp2f(sT[m][g][3] * T2 - M2));
        *(uint2*)(Ptw + (m * 16 + l16) * PSTR + g * 16 + quad * 4) = pw;
      }
    }

    f16x8 pa[2][2];
#pragma unroll
    for (int m = 0; m < 2; m++) {
      pa[m][0] = *(const f16x8*)(Ptw + (m * 16 + l16) * PSTR + quad * 8);
      pa[m][1] = *(const f16x8*)(Ptw + (m * 16 + l16) * PSTR + quad * 8 + 32);
    }

#pragma unroll
    for (int g = 0; g < 4; g++) {
      const unsigned short* vb0 = Vt + (g * 16 + l16) * KTS + quad * 8;
      f16x8 vf0 = *(const f16x8*)vb0;
      f16x8 vf1 = *(const f16x8*)(vb0 + 32);
#pragma unroll
      for (int m = 0; m < 2; m++) {
        oacc[m][g] = __builtin_amdgcn_mfma_f32_16x16x32_f16(vf0, pa[m][0], oacc[m][g], 0, 0, 0);
        oacc[m][g] = __builtin_amdgcn_mfma_f32_16x16x32_f16(vf1, pa[m][1], oacc[m][g], 0, 0, 0);
      }
    }
  }

#pragma unroll
  for (int m = 0; m < 2; m++) {
    float inv = 1.0f / __shfl(oacc[m][3][0], l16);
    size_t obase = ((size_t)b * Nn + q0 + wave * 32 + m * 16 + l16) * Cc + h * HD;
#pragma unroll
    for (int g = 0; g < 3; g++) {
      ushort4 sv;
      sv.x = f2h(oacc[m][g][0] * inv);
      sv.y = f2h(oacc[m][g][1] * inv);
      sv.z = f2h(oacc[m][g][2] * inv);
      sv.w = f2h(oacc[m][g][3] * inv);
      *(ushort4*)(obh + obase + g * 16 + quad * 4) = sv;
    }
  }
}

// ---------------------------------------------------------------------------
// Kernel F: projection GEMM, f16 single-term, async global_load_lds staging.
// ---------------------------------------------------------------------------
__global__ __launch_bounds__(256, 4) void proj_mfma(
    const unsigned short* __restrict__ pwh,
    const unsigned short* __restrict__ obh,
    const float* __restrict__ pb, float* __restrict__ out) {
  __shared__ unsigned short Ash[128 * 64];
  __shared__ unsigned short Bsh[128 * 64];
  const int b  = blockIdx.z;
  const int c0m = blockIdx.y * 128;
  const int n0 = blockIdx.x * 128;
  const int tid = threadIdx.x;
  const int wave = tid >> 6, lane = tid & 63;
  const int quad = lane >> 4, l16 = lane & 15;
  const int wm = (wave >> 1) * 64, wn = (wave & 1) * 64;

  f32x4 acc[4][4];
#pragma unroll
  for (int mi = 0; mi < 4; mi++)
#pragma unroll
    for (int ni = 0; ni < 4; ni++) acc[mi][ni] = (f32x4){0.f, 0.f, 0.f, 0.f};

  const int sw = l16 & 7;

  for (int j0 = 0; j0 < Cc; j0 += 64) {
    __syncthreads();
#pragma unroll
    for (int s = 0; s < 4; s++) {
      int r  = s * 32 + wave * 8 + (lane >> 3);
      int cg = ((lane & 7) ^ (lane >> 3)) * 8;
      gload_lds16(pwh + (size_t)(c0m + r) * Cc + j0 + cg,
                  &Ash[(s * 32 + wave * 8) * 64]);
      gload_lds16(obh + ((size_t)b * Nn + n0 + r) * Cc + j0 + cg,
                  &Bsh[(s * 32 + wave * 8) * 64]);
    }
    __syncthreads();

#pragma unroll
    for (int ks = 0; ks < 64; ks += 32) {
      const int ach = (((ks >> 3) + quad) ^ sw) * 8;
      f16x8 ah[4], bh[4];
#pragma unroll
      for (int mi = 0; mi < 4; mi++)
        ah[mi] = *(const f16x8*)&Ash[(wm + mi * 16 + l16) * 64 + ach];
#pragma unroll
      for (int ni = 0; ni < 4; ni++)
        bh[ni] = *(const f16x8*)&Bsh[(wn + ni * 16 + l16) * 64 + ach];
#pragma unroll
      for (int mi = 0; mi < 4; mi++)
#pragma unroll
        for (int ni = 0; ni < 4; ni++)
          acc[mi][ni] = __builtin_amdgcn_mfma_f32_16x16x32_f16(ah[mi], bh[ni], acc[mi][ni], 0, 0, 0);
    }
  }

#pragma unroll
  for (int mi = 0; mi < 4; mi++) {
#pragma unroll
    for (int r = 0; r < 4; r++) {
      int c = c0m + wm + mi * 16 + quad * 4 + r;
      float bvv = pb[c];
#pragma unroll
      for (int ni = 0; ni < 4; ni++) {
        int n = n0 + wn + ni * 16 + l16;
        out[((size_t)b * Cc + c) * Nn + n] = acc[mi][ni][r] + bvv;
      }
    }
  }
}

// ---------------------------------------------------------------------------
extern "C" void kernel_launch(void* const* d_in, const int* in_sizes, int n_in,
                              void* d_out, int out_size, void* d_ws, size_t ws_size,
                              hipStream_t stream) {
  const float* x     = (const float*)d_in[0];
  const float* temp  = (const float*)d_in[1];
  const float* qkv_w = (const float*)d_in[2];
  const float* qkv_b = (const float*)d_in[3];
  const float* pw    = (const float*)d_in[4];
  const float* pb    = (const float*)d_in[5];
  float* out = (float*)d_out;

  const size_t QKN = (size_t)Bb * NH * Nn * D64;   // 8,388,608
  const size_t WQN = (size_t)C3 * Cc;              // 442,368
  const size_t PWN = (size_t)Cc * Cc;              // 147,456

  unsigned short* Qh  = (unsigned short*)d_ws;
  unsigned short* Kh  = Qh + QKN;
  unsigned short* VhT = Kh + QKN;                  // [B][NH][64][N]
  unsigned short* Wqh = VhT + QKN;
  unsigned short* Pwh = Wqh + WQN;
  unsigned short* Xth = Pwh + PWN;                 // aliased by Obh after qkv
  unsigned short* Obh = Xth;

  prep_kernel<<<3328, 256, 0, stream>>>(qkv_w, pw, Wqh, Pwh, VhT);
  xsplit_kernel<<<dim3(Nn / 64, Cc / 64, Bb), 256, 0, stream>>>(x, Xth);
  qkv_mfma<<<dim3(Nn / 128, C3 / 96, Bb), 256, 0, stream>>>(Wqh, Xth, qkv_b, Qh, Kh, VhT);
  attn_mfma<<<1024, 256, 0, stream>>>(Qh, Kh, VhT, temp, Obh);
  proj_mfma<<<dim3(Nn / 128, Cc / 128, Bb), 256, 0, stream>>>(Pwh, Obh, pb, out);
}